// Round 3
// baseline (2233.353 us; speedup 1.0000x reference)
//
#include <hip/hip_runtime.h>
#include <stdint.h>

#define B_ 256
#define P_ 620
#define C_ 512
#define T_ 32
#define V_ 140
#define H_ 256
#define A_ 256
#define KC 672   // padded concat K: 140(x) + 256(ctx) + 256(h) = 652 -> 672 = 21*32
#define LOG2E 1.4426950408889634f

typedef unsigned short u16;
typedef __attribute__((ext_vector_type(8))) short bf16x8;
typedef __attribute__((ext_vector_type(4))) float f32x4;

__device__ __forceinline__ float bf2f(u16 u) {
  union { unsigned int i; float f; } v; v.i = ((unsigned int)u) << 16; return v.f;
}
__device__ __forceinline__ float bfu_lo(unsigned int u) {
  union { unsigned int i; float f; } v; v.i = u << 16; return v.f;
}
__device__ __forceinline__ float bfu_hi(unsigned int u) {
  union { unsigned int i; float f; } v; v.i = u & 0xffff0000u; return v.f;
}
__device__ __forceinline__ u16 f2bf(float f) {
  union { float f; unsigned int i; } v; v.f = f;
  unsigned int x = v.i;
  return (u16)((x + 0x7fffu + ((x >> 16) & 1u)) >> 16);
}
__device__ __forceinline__ float sigf(float x) {
  return 1.f / (1.f + __builtin_exp2f(-x * LOG2E));
}
__device__ __forceinline__ float tanhfast(float x) {
  return 1.f - 2.f / (__builtin_exp2f(2.f * LOG2E * x) + 1.f);
}
// dtype-flexible scalar load (f32 flag is block-uniform)
__device__ __forceinline__ float ld_any(const void* p, size_t idx, int f32) {
  return f32 ? ((const float*)p)[idx] : bf2f(((const u16*)p)[idx]);
}
// dtype-flexible 8-element row chunk -> bf16x8 (off multiple of 8)
__device__ __forceinline__ bf16x8 ld8_any(const void* base, size_t off, int f32) {
  if (f32) {
    const float4* p = (const float4*)((const float*)base + off);
    float4 x = p[0], y = p[1];
    bf16x8 r;
    r[0] = (short)f2bf(x.x); r[1] = (short)f2bf(x.y);
    r[2] = (short)f2bf(x.z); r[3] = (short)f2bf(x.w);
    r[4] = (short)f2bf(y.x); r[5] = (short)f2bf(y.y);
    r[6] = (short)f2bf(y.z); r[7] = (short)f2bf(y.w);
    return r;
  }
  return *(const bf16x8*)((const u16*)base + off);
}

// ---------------- dtype detection: low u16 halves of f32 words are garbage ---
__global__ void k_detect(const unsigned int* __restrict__ img, int* __restrict__ flag) {
  __shared__ int mx[256];
  unsigned int u = img[threadIdx.x];
  mx[threadIdx.x] = (int)((u >> 7) & 0xffu);  // bf16 exponent of LOW u16
  __syncthreads();
  if (threadIdx.x == 0) {
    int m = 0;
    #pragma unroll 16
    for (int i = 0; i < 256; i++) m = (mx[i] > m) ? mx[i] : m;
    *flag = (m >= 0x90) ? 1 : 0;  // bf16 N(0,1) data never reaches 2^17
  }
}

// ---------------- init: permuted W_cat, biases, weight conversion, inp/h/c ---
__global__ void k_init(const void* __restrict__ W_ih, const void* __restrict__ W_hh,
                       const void* __restrict__ b_ih, const void* __restrict__ b_hh,
                       const void* __restrict__ targets,
                       const void* __restrict__ Hc_w, const void* __restrict__ Hc_b,
                       const void* __restrict__ Cd_w, const void* __restrict__ Cd_b,
                       u16* __restrict__ W_cat, float* __restrict__ bias_cat,
                       u16* __restrict__ inp0, u16* __restrict__ inp1,
                       float* __restrict__ h_buf, float* __restrict__ c_buf,
                       u16* __restrict__ Hc_wb, float* __restrict__ hcb_f,
                       u16* __restrict__ Cd_wb, float* __restrict__ cdb_f,
                       const int* __restrict__ flag) {
  const int f32 = *flag;
  const int tid = blockIdx.x * blockDim.x + threadIdx.x;
  const int nthr = gridDim.x * blockDim.x;
  // W_cat row jq = j*4+q  <->  orig gate row n = q*256 + j ; cols [W_ih | W_hh | 0pad]
  for (int idx = tid; idx < 1024 * KC; idx += nthr) {
    int jq = idx / KC, k = idx - jq * KC;
    int j = jq >> 2, q = jq & 3, n = q * H_ + j;
    u16 v = 0;
    if (k < 396) v = f2bf(ld_any(W_ih, (size_t)n * 396 + k, f32));
    else if (k < 652) v = f2bf(ld_any(W_hh, (size_t)n * H_ + (k - 396), f32));
    W_cat[idx] = v;
  }
  for (int n = tid; n < 1024; n += nthr) {
    int j = n >> 2, q = n & 3, on = q * H_ + j;
    bias_cat[n] = ld_any(b_ih, on, f32) + ld_any(b_hh, on, f32);
  }
  for (int idx = tid; idx < B_ * KC; idx += nthr) {
    int b = idx / KC, k = idx - b * KC;
    u16 x0 = 0;
    if (k < V_) x0 = f2bf(ld_any(targets, (size_t)b * T_ * V_ + k, f32));
    inp0[idx] = x0;
    inp1[idx] = 0;
  }
  for (int idx = tid; idx < B_ * H_; idx += nthr) { h_buf[idx] = 0.f; c_buf[idx] = 0.f; }
  for (int idx = tid; idx < H_ * A_; idx += nthr) Hc_wb[idx] = f2bf(ld_any(Hc_w, idx, f32));
  for (int idx = tid; idx < V_ * H_; idx += nthr) Cd_wb[idx] = f2bf(ld_any(Cd_w, idx, f32));
  for (int n = tid; n < A_; n += nthr) hcb_f[n] = ld_any(Hc_b, n, f32);
  for (int n = tid; n < V_; n += nthr) cdb_f[n] = ld_any(Cd_b, n, f32);
}

// ---------------- phase 1: attn_img = img @ Ic_w^T + Ic_b (bf16 out) ---------
__global__ __launch_bounds__(256) void k_proj(const void* __restrict__ img,
                                              const void* __restrict__ Ic_w,
                                              const void* __restrict__ Ic_b,
                                              u16* __restrict__ attn_img,
                                              const int* __restrict__ flag) {
  __shared__ __align__(16) short As[128 * 32];
  __shared__ __align__(16) short Bs[128 * 32];
  const int f32 = *flag;
  const int tid = threadIdx.x;
  const int lane = tid & 63, w = tid >> 6;
  const int m0 = blockIdx.x * 128;
  const int n0 = blockIdx.y * 128;
  f32x4 acc[4][4] = {};
  const int wm = w & 1, wn = w >> 1;
  const int fr = lane & 15, fq = lane >> 4;
  const int srow = tid >> 2, scol = (tid & 3) * 8;
  for (int kt = 0; kt < C_; kt += 32) {
    // register-roundtrip staging (prefetch before barrier)
    bf16x8 a0 = ld8_any(img, (size_t)(m0 + srow) * C_ + kt + scol, f32);
    bf16x8 a1 = ld8_any(img, (size_t)(m0 + srow + 64) * C_ + kt + scol, f32);
    bf16x8 b0 = ld8_any(Ic_w, (size_t)(n0 + srow) * C_ + kt + scol, f32);
    bf16x8 b1 = ld8_any(Ic_w, (size_t)(n0 + srow + 64) * C_ + kt + scol, f32);
    __syncthreads();  // previous iteration's fragment reads complete
    *(bf16x8*)(As + tid * 8) = a0;
    *(bf16x8*)(As + (tid + 256) * 8) = a1;
    *(bf16x8*)(Bs + tid * 8) = b0;
    *(bf16x8*)(Bs + (tid + 256) * 8) = b1;
    __syncthreads();
    bf16x8 af[4], bfr[4];
    #pragma unroll
    for (int i = 0; i < 4; i++)
      af[i] = *(const bf16x8*)(As + (wm * 64 + i * 16 + fr) * 32 + fq * 8);
    #pragma unroll
    for (int j = 0; j < 4; j++)
      bfr[j] = *(const bf16x8*)(Bs + (wn * 64 + j * 16 + fr) * 32 + fq * 8);
    #pragma unroll
    for (int i = 0; i < 4; i++)
      #pragma unroll
      for (int j = 0; j < 4; j++)
        acc[i][j] = __builtin_amdgcn_mfma_f32_16x16x32_bf16(af[i], bfr[j], acc[i][j], 0, 0, 0);
  }
  #pragma unroll
  for (int i = 0; i < 4; i++) {
    #pragma unroll
    for (int j = 0; j < 4; j++) {
      const int col = n0 + wn * 64 + j * 16 + fr;
      const float bias = ld_any(Ic_b, col, f32);
      #pragma unroll
      for (int rr = 0; rr < 4; rr++) {
        const int row = m0 + wm * 64 + i * 16 + fq * 4 + rr;
        attn_img[(size_t)row * A_ + col] = f2bf(acc[i][j][rr] + bias);
      }
    }
  }
}

// ---------------- per step: out(prev) + q + online-softmax ctx ---------------
__global__ __launch_bounds__(512) void k_attn(
    const u16* __restrict__ Hc_wb, const float* __restrict__ hcb_f,
    const u16* __restrict__ Cd_wb, const float* __restrict__ cdb_f,
    const u16* __restrict__ attn_img, const float* __restrict__ h_buf,
    u16* __restrict__ inp_cat, void* __restrict__ d_out, int t,
    const int* __restrict__ flag) {
  __shared__ float h_s[H_];
  __shared__ float q_s[A_];
  __shared__ __align__(16) float ctx_s[8][A_];
  __shared__ float red_m[8], red_l[8];
  const int f32 = *flag;
  const int b = blockIdx.x;
  const int tid = threadIdx.x;
  const int lane = tid & 63, w = tid >> 6;

  if (tid < H_) h_s[tid] = h_buf[b * H_ + tid];
  __syncthreads();

  if (tid < A_) {  // q = h @ Hc_w^T + Hc_b
    float acc = hcb_f[tid];
    const uint2* wr = (const uint2*)(Hc_wb + tid * H_);
    #pragma unroll 8
    for (int j = 0; j < H_ / 4; j++) {
      uint2 u = wr[j];
      acc += bfu_lo(u.x) * h_s[4 * j] + bfu_hi(u.x) * h_s[4 * j + 1]
           + bfu_lo(u.y) * h_s[4 * j + 2] + bfu_hi(u.y) * h_s[4 * j + 3];
    }
    q_s[tid] = acc;
  } else if (t > 0 && tid < A_ + V_) {  // out_{t-1} = h @ Cd_w^T + Cd_b
    const int v = tid - A_;
    float acc = cdb_f[v];
    const uint2* wr = (const uint2*)(Cd_wb + v * H_);
    #pragma unroll 8
    for (int j = 0; j < H_ / 4; j++) {
      uint2 u = wr[j];
      acc += bfu_lo(u.x) * h_s[4 * j] + bfu_hi(u.x) * h_s[4 * j + 1]
           + bfu_lo(u.y) * h_s[4 * j + 2] + bfu_hi(u.y) * h_s[4 * j + 3];
    }
    const size_t oo = (size_t)b * T_ * V_ + (size_t)(t - 1) * V_ + v;
    if (f32) ((float*)d_out)[oo] = acc;
    else ((u16*)d_out)[oo] = f2bf(acc);
    inp_cat[b * KC + v] = f2bf(acc);
  }
  __syncthreads();

  const float q0 = q_s[lane * 4 + 0], q1 = q_s[lane * 4 + 1];
  const float q2 = q_s[lane * 4 + 2], q3 = q_s[lane * 4 + 3];
  const uint2* ap = (const uint2*)(attn_img + (size_t)b * P_ * A_);
  const float sc = 0.0625f * LOG2E;  // 1/sqrt(A) folded with log2(e)

  float m0v = -3.0e38f, l0 = 0.f, a0 = 0.f, a1 = 0.f, a2 = 0.f, a3 = 0.f;
  float m1v = -3.0e38f, l1 = 0.f, b0 = 0.f, b1 = 0.f, b2 = 0.f, b3 = 0.f;

  for (int p = w; p < P_; p += 16) {
    const int p2 = p + 8;
    const int p2c = (p2 < P_) ? p2 : (P_ - 1);
    uint2 u = ap[p * 64 + lane];
    uint2 u2 = ap[p2c * 64 + lane];
    {
      float v0 = bfu_lo(u.x), v1 = bfu_hi(u.x), v2 = bfu_lo(u.y), v3 = bfu_hi(u.y);
      float s = q0 * v0 + q1 * v1 + q2 * v2 + q3 * v3;
      s += __shfl_xor(s, 32); s += __shfl_xor(s, 16); s += __shfl_xor(s, 8);
      s += __shfl_xor(s, 4);  s += __shfl_xor(s, 2);  s += __shfl_xor(s, 1);
      s *= sc;
      float mn = fmaxf(m0v, s);
      float al = __builtin_exp2f(m0v - mn);
      float es = __builtin_exp2f(s - mn);
      l0 = l0 * al + es;
      a0 = a0 * al + es * v0; a1 = a1 * al + es * v1;
      a2 = a2 * al + es * v2; a3 = a3 * al + es * v3;
      m0v = mn;
    }
    {
      float v0 = bfu_lo(u2.x), v1 = bfu_hi(u2.x), v2 = bfu_lo(u2.y), v3 = bfu_hi(u2.y);
      float s = q0 * v0 + q1 * v1 + q2 * v2 + q3 * v3;
      s += __shfl_xor(s, 32); s += __shfl_xor(s, 16); s += __shfl_xor(s, 8);
      s += __shfl_xor(s, 4);  s += __shfl_xor(s, 2);  s += __shfl_xor(s, 1);
      s *= sc;
      if (p2 >= P_) s = -3.0e38f;   // mask tail (m1v already finite here)
      float mn = fmaxf(m1v, s);
      float al = __builtin_exp2f(m1v - mn);
      float es = __builtin_exp2f(s - mn);
      l1 = l1 * al + es;
      b0 = b0 * al + es * v0; b1 = b1 * al + es * v1;
      b2 = b2 * al + es * v2; b3 = b3 * al + es * v3;
      m1v = mn;
    }
  }
  // merge the two chains
  float mw = fmaxf(m0v, m1v);
  float e0 = __builtin_exp2f(m0v - mw), e1 = __builtin_exp2f(m1v - mw);
  float lw = l0 * e0 + l1 * e1;
  float c0 = a0 * e0 + b0 * e1, c1 = a1 * e0 + b1 * e1;
  float c2 = a2 * e0 + b2 * e1, c3 = a3 * e0 + b3 * e1;

  ((float4*)ctx_s[w])[lane] = make_float4(c0, c1, c2, c3);
  if (lane == 0) { red_m[w] = mw; red_l[w] = lw; }
  __syncthreads();

  if (tid < A_) {
    float mt = red_m[0];
    #pragma unroll
    for (int i = 1; i < 8; i++) mt = fmaxf(mt, red_m[i]);
    float lt = 0.f, acc = 0.f;
    #pragma unroll
    for (int i = 0; i < 8; i++) {
      float bw = __builtin_exp2f(red_m[i] - mt);
      lt += red_l[i] * bw;
      acc += ctx_s[i][tid] * bw;
    }
    inp_cat[b * KC + V_ + tid] = f2bf(acc / lt);
  }
}

// ---------------- per step: gates GEMM (MFMA) + fused LSTM cell --------------
__global__ __launch_bounds__(256) void k_gates(
    const u16* __restrict__ W_cat, const float* __restrict__ bias_cat,
    const u16* __restrict__ inp_in, u16* __restrict__ inp_out,
    float* __restrict__ h_buf, float* __restrict__ c_buf) {
  __shared__ __align__(16) short As[32 * 32];
  __shared__ __align__(16) short Bs[128 * 32];
  __shared__ __align__(16) float gs[32 * 128];
  const int tid = threadIdx.x;
  const int lane = tid & 63, w = tid >> 6;
  const int m0 = blockIdx.x * 32;    // batch tile
  const int n0 = blockIdx.y * 128;   // permuted-gate-row tile
  f32x4 acc[2][2] = {};
  const int fr = lane & 15, fq = lane >> 4;
  const int srow = tid >> 2, scol = (tid & 3) * 8;
  for (int kt = 0; kt < KC; kt += 32) {
    bf16x8 av = {};
    if (tid < 128) av = *(const bf16x8*)(inp_in + (size_t)(m0 + srow) * KC + kt + scol);
    bf16x8 b0 = *(const bf16x8*)(W_cat + (size_t)(n0 + srow) * KC + kt + scol);
    bf16x8 b1 = *(const bf16x8*)(W_cat + (size_t)(n0 + srow + 64) * KC + kt + scol);
    __syncthreads();
    if (tid < 128) *(bf16x8*)(As + tid * 8) = av;
    *(bf16x8*)(Bs + tid * 8) = b0;
    *(bf16x8*)(Bs + (tid + 256) * 8) = b1;
    __syncthreads();
    bf16x8 af0 = *(const bf16x8*)(As + (fr) * 32 + fq * 8);
    bf16x8 af1 = *(const bf16x8*)(As + (16 + fr) * 32 + fq * 8);
    bf16x8 bf0 = *(const bf16x8*)(Bs + (w * 32 + fr) * 32 + fq * 8);
    bf16x8 bf1 = *(const bf16x8*)(Bs + (w * 32 + 16 + fr) * 32 + fq * 8);
    acc[0][0] = __builtin_amdgcn_mfma_f32_16x16x32_bf16(af0, bf0, acc[0][0], 0, 0, 0);
    acc[0][1] = __builtin_amdgcn_mfma_f32_16x16x32_bf16(af0, bf1, acc[0][1], 0, 0, 0);
    acc[1][0] = __builtin_amdgcn_mfma_f32_16x16x32_bf16(af1, bf0, acc[1][0], 0, 0, 0);
    acc[1][1] = __builtin_amdgcn_mfma_f32_16x16x32_bf16(af1, bf1, acc[1][1], 0, 0, 0);
  }
  __syncthreads();
  #pragma unroll
  for (int i = 0; i < 2; i++)
    #pragma unroll
    for (int j = 0; j < 2; j++) {
      const int n = w * 32 + j * 16 + fr;
      const float bias = bias_cat[n0 + n];
      #pragma unroll
      for (int rr = 0; rr < 4; rr++) {
        const int mm = i * 16 + fq * 4 + rr;
        gs[mm * 128 + n] = acc[i][j][rr] + bias;
      }
    }
  __syncthreads();
  // cell: each (b,j) pair exactly once; gs cols jl*4..+3 = [i,f,g,o]
  #pragma unroll
  for (int k = 0; k < 4; k++) {
    const int pair = tid + k * 256;
    const int bl = pair >> 5, jl = pair & 31;
    const float4 g4 = *(const float4*)(gs + bl * 128 + jl * 4);
    const int bg = m0 + bl, jg = (n0 >> 2) + jl;
    const float co = c_buf[bg * H_ + jg];
    const float is = sigf(g4.x), fs = sigf(g4.y);
    const float gt = tanhfast(g4.z), os = sigf(g4.w);
    const float cn = fs * co + is * gt;
    const float h2 = os * tanhfast(cn);
    c_buf[bg * H_ + jg] = cn;
    h_buf[bg * H_ + jg] = h2;
    inp_out[bg * KC + (V_ + A_) + jg] = f2bf(h2);
  }
}

// ---------------- final out for t = T-1 --------------------------------------
__global__ __launch_bounds__(256) void k_outfin(const u16* __restrict__ Cd_wb,
                                                const float* __restrict__ cdb_f,
                                                const float* __restrict__ h_buf,
                                                void* __restrict__ d_out,
                                                const int* __restrict__ flag) {
  __shared__ float h_s[H_];
  const int f32 = *flag;
  const int b = blockIdx.x, tid = threadIdx.x;
  if (tid < H_) h_s[tid] = h_buf[b * H_ + tid];
  __syncthreads();
  if (tid < V_) {
    float acc = cdb_f[tid];
    const uint2* wr = (const uint2*)(Cd_wb + tid * H_);
    #pragma unroll 8
    for (int j = 0; j < H_ / 4; j++) {
      uint2 u = wr[j];
      acc += bfu_lo(u.x) * h_s[4 * j] + bfu_hi(u.x) * h_s[4 * j + 1]
           + bfu_lo(u.y) * h_s[4 * j + 2] + bfu_hi(u.y) * h_s[4 * j + 3];
    }
    const size_t oo = (size_t)b * T_ * V_ + (size_t)(T_ - 1) * V_ + tid;
    if (f32) ((float*)d_out)[oo] = acc;
    else ((u16*)d_out)[oo] = f2bf(acc);
  }
}

extern "C" void kernel_launch(void* const* d_in, const int* in_sizes, int n_in,
                              void* d_out, int out_size, void* d_ws, size_t ws_size,
                              hipStream_t stream) {
  (void)in_sizes; (void)n_in; (void)out_size; (void)ws_size;
  const void* img  = d_in[0];
  const void* tgt  = d_in[1];
  const void* Ic_w = d_in[2];
  const void* Ic_b = d_in[3];
  const void* Hc_w = d_in[4];
  const void* Hc_b = d_in[5];
  const void* W_ih = d_in[6];
  const void* W_hh = d_in[7];
  const void* b_ih = d_in[8];
  const void* b_hh = d_in[9];
  const void* Cd_w = d_in[10];
  const void* Cd_b = d_in[11];

  char* ws = (char*)d_ws;
  size_t off = 0;
  auto alloc = [&](size_t bytes) -> void* {
    void* p = ws + off;
    off += (bytes + 255) & ~(size_t)255;
    return p;
  };
  u16*   attn_img = (u16*)alloc((size_t)B_ * P_ * A_ * 2);
  u16*   W_cat    = (u16*)alloc((size_t)1024 * KC * 2);
  float* bias_cat = (float*)alloc(1024 * 4);
  u16*   inp0     = (u16*)alloc((size_t)B_ * KC * 2);
  u16*   inp1     = (u16*)alloc((size_t)B_ * KC * 2);
  float* h_buf    = (float*)alloc((size_t)B_ * H_ * 4);
  float* c_buf    = (float*)alloc((size_t)B_ * H_ * 4);
  u16*   Hc_wb    = (u16*)alloc((size_t)H_ * A_ * 2);
  float* hcb_f    = (float*)alloc(A_ * 4);
  u16*   Cd_wb    = (u16*)alloc((size_t)V_ * H_ * 2);
  float* cdb_f    = (float*)alloc(V_ * 4);
  int*   flag     = (int*)alloc(256);

  k_detect<<<dim3(1), dim3(256), 0, stream>>>((const unsigned int*)img, flag);
  k_init<<<dim3(512), dim3(256), 0, stream>>>(W_ih, W_hh, b_ih, b_hh, tgt,
                                              Hc_w, Hc_b, Cd_w, Cd_b,
                                              W_cat, bias_cat, inp0, inp1, h_buf, c_buf,
                                              Hc_wb, hcb_f, Cd_wb, cdb_f, flag);
  k_proj<<<dim3(1240, 2), dim3(256), 0, stream>>>(img, Ic_w, Ic_b, attn_img, flag);
  for (int t = 0; t < T_; t++) {
    u16* inp  = (t & 1) ? inp1 : inp0;
    u16* inpn = (t & 1) ? inp0 : inp1;
    k_attn<<<dim3(B_), dim3(512), 0, stream>>>(Hc_wb, hcb_f, Cd_wb, cdb_f, attn_img,
                                               h_buf, inp, d_out, t, flag);
    k_gates<<<dim3(8, 8), dim3(256), 0, stream>>>(W_cat, bias_cat, inp, inpn, h_buf, c_buf);
  }
  k_outfin<<<dim3(B_), dim3(256), 0, stream>>>(Cd_wb, cdb_f, h_buf, d_out, flag);
}